// Round 1
// baseline (398.418 us; speedup 1.0000x reference)
//
#include <hip/hip_runtime.h>

// BatchSplitFF: DM=1024, NE=16, ES=4 (NES=64 expert pairs), ESZ=64,
// BATCH*SEQ = 8*2048 tokens -> 1024 groups of 16 tokens.
#define DM   1024
#define NES  64
#define ESZ  64
#define NG   1024
#define TOK  16

typedef __bf16 bf16;
typedef __bf16 bf16x4 __attribute__((ext_vector_type(4)));
typedef __bf16 bf16x8 __attribute__((ext_vector_type(8)));
typedef float  f32x4  __attribute__((ext_vector_type(4)));

// ---------------- K0: cast weights to bf16 ----------------
// f1 [d][es][f] -> f1t bf16 [es][d][f]   (per-es slice contiguous)
// f2 [es][f][d] -> f2b bf16 [es][f][d]   (straight cast; already es-major)
__global__ __launch_bounds__(256) void k0_cast(const float* __restrict__ f1,
                                               const float* __restrict__ f2,
                                               bf16* __restrict__ f1t,
                                               bf16* __restrict__ f2b) {
    int i = blockIdx.x * 256 + threadIdx.x;   // one float4 of each tensor
    {   // f2 straight cast
        float4 v = ((const float4*)f2)[i];
        bf16x4 o = {(bf16)v.x, (bf16)v.y, (bf16)v.z, (bf16)v.w};
        *(bf16x4*)(f2b + (size_t)i * 4) = o;
    }
    {   // f1 permute [d][es][f] -> [es][d][f]
        int o  = i * 4;
        int es = o >> 16;
        int d  = (o >> 6) & 1023;
        int f  = o & 63;
        float4 v = *(const float4*)(f1 + (size_t)d * 4096 + es * 64 + f);
        bf16x4 ob = {(bf16)v.x, (bf16)v.y, (bf16)v.z, (bf16)v.w};
        *(bf16x4*)(f1t + (size_t)o) = ob;
    }
}

// ---------------- K1: fp32 logits + argmax ----------------
// One block per group. logits[t][es] = x[group,t,:] . controller[:,es] + tie(t)
// argmax over t per es, ties -> larger t (matches the linspace tiebreaker).
__global__ __launch_bounds__(256) void k1_logits(const float* __restrict__ x,
                                                 const float* __restrict__ ctrl,
                                                 int* __restrict__ sel) {
    __shared__ __align__(16) float xs[TOK * 128];   // 16 x 128 d-chunk
    __shared__ float sl[TOK * NES];
    const int bg  = blockIdx.x;
    const int tid = threadIdx.x;
    const int es  = tid & 63;
    const int tq  = tid >> 6;            // wave id 0..3, handles t = 4*tq..4*tq+3
    const float* xg = x + (size_t)bg * (TOK * DM);
    float acc[4] = {0.f, 0.f, 0.f, 0.f};
    for (int d0 = 0; d0 < DM; d0 += 128) {
        __syncthreads();
        #pragma unroll
        for (int c = 0; c < 2; ++c) {
            int idx = tid + c * 256;     // 512 float4 slots
            int tr  = idx >> 5;          // 32 float4 per row
            int c4  = idx & 31;
            float4 v = *(const float4*)(xg + tr * DM + d0 + c4 * 4);
            *(float4*)(xs + tr * 128 + c4 * 4) = v;
        }
        __syncthreads();
        for (int dl = 0; dl < 128; ++dl) {
            float c = ctrl[(d0 + dl) * 64 + es];
            #pragma unroll
            for (int i = 0; i < 4; ++i)
                acc[i] += xs[(tq * 4 + i) * 128 + dl] * c;   // LDS broadcast
        }
    }
    #pragma unroll
    for (int i = 0; i < 4; ++i) {
        int t = tq * 4 + i;
        sl[t * NES + es] = acc[i] + (float)t * (1e-6f / 15.f);
    }
    __syncthreads();
    if (tid < NES) {
        float best = -1e30f; int bi = 0;
        #pragma unroll
        for (int t = 0; t < TOK; ++t) {
            float v = sl[t * NES + tid];
            if (v >= best) { best = v; bi = t; }   // >= : later t wins ties
        }
        sel[bg * NES + tid] = bi;
    }
}

// ---------------- K2: FFN1 (gather + GEMM + bias + relu) ----------------
// Per (es, 128-group tile): inner[es][g][f] = relu(Xsel @ F1_es + bias_es)
// M=128 (groups), N=64 (f), K=1024 (d), MFMA 16x16x32 bf16.
__global__ __launch_bounds__(256) void k2_ffn1(const float* __restrict__ x,
                                               const bf16* __restrict__ f1t,
                                               const float* __restrict__ bias,
                                               const int* __restrict__ sel,
                                               bf16* __restrict__ inner) {
    __shared__ int  sel_s[128];
    __shared__ __align__(16) bf16 As[128 * 40];   // [m=128][k=32], stride 40 (pad)
    __shared__ __align__(16) bf16 Bs[64 * 40];    // [n=64][k=32], stride 40
    const int es  = blockIdx.y;
    const int g0  = blockIdx.x * 128;
    const int tid = threadIdx.x;
    if (tid < 128) sel_s[tid] = sel[(g0 + tid) * 64 + es];
    __syncthreads();

    const int w = tid >> 6, l = tid & 63, quad = l >> 4, lr = l & 15;
    // hoist gathered-row bases for staging
    int tokrow[4];
    #pragma unroll
    for (int p = 0; p < 4; ++p) {
        int grow = p * 32 + (tid >> 3);
        tokrow[p] = (g0 + grow) * 16 + sel_s[grow];
    }
    const int c4 = (tid & 7) * 4;
    const bf16* f1es = f1t + (size_t)es * (DM * ESZ);

    f32x4 acc[2][4];
    #pragma unroll
    for (int mt = 0; mt < 2; ++mt)
        #pragma unroll
        for (int nt = 0; nt < 4; ++nt)
            acc[mt][nt] = (f32x4){0.f, 0.f, 0.f, 0.f};

    for (int k0 = 0; k0 < DM; k0 += 32) {
        // stage A: gather 128 selected rows (fp32 -> bf16)
        #pragma unroll
        for (int p = 0; p < 4; ++p) {
            int grow = p * 32 + (tid >> 3);
            float4 v = *(const float4*)(x + (size_t)tokrow[p] * DM + k0 + c4);
            bf16x4 ob = {(bf16)v.x, (bf16)v.y, (bf16)v.z, (bf16)v.w};
            *(bf16x4*)(As + grow * 40 + c4) = ob;
        }
        // stage B: f1t slice [32 d][64 f] -> Bs[f][d] (transpose)
        {
            int idx = tid * 8;
            int dl = idx >> 6, f0 = idx & 63;
            bf16x8 v = *(const bf16x8*)(f1es + (size_t)(k0 + dl) * 64 + f0);
            #pragma unroll
            for (int j = 0; j < 8; ++j) Bs[(f0 + j) * 40 + dl] = v[j];
        }
        __syncthreads();
        bf16x8 av[2], bv[4];
        #pragma unroll
        for (int mt = 0; mt < 2; ++mt)
            av[mt] = *(const bf16x8*)(As + (w * 32 + mt * 16 + lr) * 40 + quad * 8);
        #pragma unroll
        for (int nt = 0; nt < 4; ++nt)
            bv[nt] = *(const bf16x8*)(Bs + (nt * 16 + lr) * 40 + quad * 8);
        #pragma unroll
        for (int mt = 0; mt < 2; ++mt)
            #pragma unroll
            for (int nt = 0; nt < 4; ++nt)
                acc[mt][nt] = __builtin_amdgcn_mfma_f32_16x16x32_bf16(
                    av[mt], bv[nt], acc[mt][nt], 0, 0, 0);
        __syncthreads();
    }
    // epilogue: bias + relu -> bf16 inner[es][g][f]
    bf16* innes = inner + (size_t)es * (NG * ESZ);
    #pragma unroll
    for (int mt = 0; mt < 2; ++mt)
        #pragma unroll
        for (int nt = 0; nt < 4; ++nt) {
            int f = nt * 16 + lr;
            float b = bias[es * 64 + f];
            #pragma unroll
            for (int r = 0; r < 4; ++r) {
                int grow = w * 32 + mt * 16 + quad * 4 + r;  // C row = quad*4+reg
                float v = acc[mt][nt][r] + b;
                v = v > 0.f ? v : 0.f;
                innes[(size_t)(g0 + grow) * 64 + f] = (bf16)v;
            }
        }
}

// ---------------- K3: FFN2 + un-permute scatter ----------------
// Block = (16-group tile, 32-d tile). Loop all 64 es: 2 MFMAs (K=64),
// scatter-accumulate into LDS acc[g][t][d]; dense write (zeros included),
// so no global memset / atomics needed.
__global__ __launch_bounds__(128) void k3_ffn2(const bf16* __restrict__ inner,
                                               const bf16* __restrict__ f2b,
                                               const int* __restrict__ sel,
                                               float* __restrict__ out) {
    __shared__ float accs[16 * 16 * 32];              // [g][t][d] 32KB
    __shared__ __align__(16) bf16 As[16 * 72];        // [m=16][k=64] stride 72
    __shared__ __align__(16) bf16 Bs[32 * 72];        // [n=32][k=64] stride 72
    __shared__ int sel_s[16 * 64];
    const int d0  = blockIdx.x * 32;
    const int g0  = blockIdx.y * 16;
    const int tid = threadIdx.x;

    #pragma unroll
    for (int j = 0; j < 2; ++j)
        ((int4*)sel_s)[tid * 2 + j] = ((const int4*)(sel + g0 * 64))[tid * 2 + j];
    #pragma unroll
    for (int i = 0; i < 16; ++i)
        ((float4*)accs)[tid + 128 * i] = (float4){0.f, 0.f, 0.f, 0.f};
    __syncthreads();

    const int w = tid >> 6, l = tid & 63, quad = l >> 4, lr = l & 15;
    for (int es = 0; es < NES; ++es) {
        {   // stage A: inner[es][g0..g0+16][0..64] (contiguous 2KB)
            int idx = tid * 8;
            int gl = idx >> 6, f0 = idx & 63;
            bf16x8 v = *(const bf16x8*)(inner + (size_t)es * (NG * 64) +
                                        (g0 + gl) * 64 + f0);
            *(bf16x8*)(As + gl * 72 + f0) = v;
        }
        #pragma unroll
        for (int c = 0; c < 2; ++c) {   // stage B: f2[es][f][d0..+32] -> Bs[d][f]
            int idx = tid * 8 + c * 1024;
            int f = idx >> 5, dl = idx & 31;
            bf16x8 v = *(const bf16x8*)(f2b + (size_t)es * (ESZ * DM) +
                                        f * 1024 + d0 + dl);
            #pragma unroll
            for (int j = 0; j < 8; ++j) Bs[(dl + j) * 72 + f] = v[j];
        }
        __syncthreads();
        bf16x8 a0 = *(const bf16x8*)(As + lr * 72 + quad * 8);
        bf16x8 a1 = *(const bf16x8*)(As + lr * 72 + 32 + quad * 8);
        bf16x8 b0 = *(const bf16x8*)(Bs + (w * 16 + lr) * 72 + quad * 8);
        bf16x8 b1 = *(const bf16x8*)(Bs + (w * 16 + lr) * 72 + 32 + quad * 8);
        f32x4 acc = {0.f, 0.f, 0.f, 0.f};
        acc = __builtin_amdgcn_mfma_f32_16x16x32_bf16(a0, b0, acc, 0, 0, 0);
        acc = __builtin_amdgcn_mfma_f32_16x16x32_bf16(a1, b1, acc, 0, 0, 0);
        #pragma unroll
        for (int r = 0; r < 4; ++r) {   // scatter: wave w owns d-half, no races
            int gl = quad * 4 + r;
            int t  = sel_s[gl * 64 + es];
            accs[(gl * 16 + t) * 32 + w * 16 + lr] += acc[r];
        }
        __syncthreads();
    }
    // dense write-out: rows (g*16+t) are contiguous output token rows
    #pragma unroll
    for (int i = 0; i < 16; ++i) {
        int fi = tid + 128 * i;
        int row = fi >> 3, q = fi & 7;
        float4 v = *(float4*)(accs + row * 32 + q * 4);
        *(float4*)(out + (size_t)(g0 * 16 + row) * DM + d0 + q * 4) = v;
    }
}

extern "C" void kernel_launch(void* const* d_in, const int* in_sizes, int n_in,
                              void* d_out, int out_size, void* d_ws, size_t ws_size,
                              hipStream_t stream) {
    const float* x    = (const float*)d_in[0];
    const float* ctrl = (const float*)d_in[1];
    const float* f1   = (const float*)d_in[2];
    const float* f2   = (const float*)d_in[3];
    const float* bias = (const float*)d_in[4];
    float* out = (float*)d_out;

    char* ws = (char*)d_ws;
    bf16* f1t   = (bf16*)(ws);                  // 8,388,608 B
    bf16* f2b   = (bf16*)(ws + 8388608);        // 8,388,608 B
    bf16* inner = (bf16*)(ws + 16777216);       // 8,388,608 B
    int*  sel   = (int*)(ws + 25165824);        //   262,144 B

    hipLaunchKernelGGL(k0_cast,   dim3(4096),   dim3(256), 0, stream, f1, f2, f1t, f2b);
    hipLaunchKernelGGL(k1_logits, dim3(1024),   dim3(256), 0, stream, x, ctrl, sel);
    hipLaunchKernelGGL(k2_ffn1,   dim3(8, 64),  dim3(256), 0, stream, x, f1t, bias, sel, inner);
    hipLaunchKernelGGL(k3_ffn2,   dim3(32, 64), dim3(128), 0, stream, inner, f2b, sel, out);
}

// Round 2
// 357.091 us; speedup vs baseline: 1.1157x; 1.1157x over previous
//
#include <hip/hip_runtime.h>

// BatchSplitFF: DM=1024, NE=16, ES=4 (NES=64 expert pairs), ESZ=64,
// BATCH*SEQ = 8*2048 tokens -> 1024 groups of 16 tokens.
#define DM   1024
#define NES  64
#define ESZ  64
#define NG   1024
#define TOK  16

typedef __bf16 bf16;
typedef __bf16 bf16x4 __attribute__((ext_vector_type(4)));
typedef __bf16 bf16x8 __attribute__((ext_vector_type(8)));
typedef float  f32x4  __attribute__((ext_vector_type(4)));

// ---------------- K0: transpose weights to bf16, MFMA-friendly layouts ----
// f1 [d][es][f] -> f1p bf16 [es][f][d]  (B-operand rows for K2: k=d contiguous)
// f2 [es][f][d] -> f2t bf16 [es][d][f]  (B-operand rows for K3: k=f contiguous)
__global__ __launch_bounds__(256) void k0_transpose(const float* __restrict__ f1,
                                                    const float* __restrict__ f2,
                                                    bf16* __restrict__ f1p,
                                                    bf16* __restrict__ f2t) {
    __shared__ float tile[64 * 65];   // stride 65: 2-way max on scalar r/w
    const int es = blockIdx.y, d0 = blockIdx.x * 64, tid = threadIdx.x;
    // ---- f1 tile: tile[d_local][f]
    #pragma unroll
    for (int i = 0; i < 4; ++i) {
        int idx = i * 256 + tid; int r = idx >> 4, c4 = (idx & 15) * 4;
        float4 v = *(const float4*)(f1 + (size_t)(d0 + r) * 4096 + es * 64 + c4);
        tile[r * 65 + c4] = v.x; tile[r * 65 + c4 + 1] = v.y;
        tile[r * 65 + c4 + 2] = v.z; tile[r * 65 + c4 + 3] = v.w;
    }
    __syncthreads();
    #pragma unroll
    for (int i = 0; i < 2; ++i) {
        int idx = i * 256 + tid; int f = idx >> 3, dl0 = (idx & 7) * 8;
        bf16x8 o;
        #pragma unroll
        for (int j = 0; j < 8; ++j) o[j] = (bf16)tile[(dl0 + j) * 65 + f];
        *(bf16x8*)(f1p + (size_t)es * 65536 + f * 1024 + d0 + dl0) = o;
    }
    __syncthreads();
    // ---- f2 tile: tile[f][d_local]
    #pragma unroll
    for (int i = 0; i < 4; ++i) {
        int idx = i * 256 + tid; int r = idx >> 4, c4 = (idx & 15) * 4;
        float4 v = *(const float4*)(f2 + (size_t)es * 65536 + r * 1024 + d0 + c4);
        tile[r * 65 + c4] = v.x; tile[r * 65 + c4 + 1] = v.y;
        tile[r * 65 + c4 + 2] = v.z; tile[r * 65 + c4 + 3] = v.w;
    }
    __syncthreads();
    #pragma unroll
    for (int i = 0; i < 2; ++i) {
        int idx = i * 256 + tid; int dl = idx >> 3, f0 = (idx & 7) * 8;
        bf16x8 o;
        #pragma unroll
        for (int j = 0; j < 8; ++j) o[j] = (bf16)tile[(f0 + j) * 65 + dl];
        *(bf16x8*)(f2t + (size_t)es * 65536 + (size_t)(d0 + dl) * 64 + f0) = o;
    }
}

// ---------------- K1: fp32 logits + argmax (UNCHANGED — numerics locked) ---
__global__ __launch_bounds__(256) void k1_logits(const float* __restrict__ x,
                                                 const float* __restrict__ ctrl,
                                                 int* __restrict__ sel) {
    __shared__ __align__(16) float xs[TOK * 128];
    __shared__ float sl[TOK * NES];
    const int bg  = blockIdx.x;
    const int tid = threadIdx.x;
    const int es  = tid & 63;
    const int tq  = tid >> 6;
    const float* xg = x + (size_t)bg * (TOK * DM);
    float acc[4] = {0.f, 0.f, 0.f, 0.f};
    for (int d0 = 0; d0 < DM; d0 += 128) {
        __syncthreads();
        #pragma unroll
        for (int c = 0; c < 2; ++c) {
            int idx = tid + c * 256;
            int tr  = idx >> 5;
            int c4  = idx & 31;
            float4 v = *(const float4*)(xg + tr * DM + d0 + c4 * 4);
            *(float4*)(xs + tr * 128 + c4 * 4) = v;
        }
        __syncthreads();
        for (int dl = 0; dl < 128; ++dl) {
            float c = ctrl[(d0 + dl) * 64 + es];
            #pragma unroll
            for (int i = 0; i < 4; ++i)
                acc[i] += xs[(tq * 4 + i) * 128 + dl] * c;
        }
    }
    #pragma unroll
    for (int i = 0; i < 4; ++i) {
        int t = tq * 4 + i;
        sl[t * NES + es] = acc[i] + (float)t * (1e-6f / 15.f);
    }
    __syncthreads();
    if (tid < NES) {
        float best = -1e30f; int bi = 0;
        #pragma unroll
        for (int t = 0; t < TOK; ++t) {
            float v = sl[t * NES + tid];
            if (v >= best) { best = v; bi = t; }
        }
        sel[bg * NES + tid] = bi;
    }
}

// ---------------- K2: FFN1 (gather + GEMM + bias + relu) ----------------
// Per (es, 128-group tile): inner[es][g][f] = relu(Xsel @ F1_es + bias_es)
// B-staging is now a contiguous b128 copy from pre-transposed f1p[es][f][d].
__global__ __launch_bounds__(256) void k2_ffn1(const float* __restrict__ x,
                                               const bf16* __restrict__ f1p,
                                               const float* __restrict__ bias,
                                               const int* __restrict__ sel,
                                               bf16* __restrict__ inner) {
    __shared__ int  sel_s[128];
    __shared__ __align__(16) bf16 As[128 * 40];   // [m=128][k=32], stride 40
    __shared__ __align__(16) bf16 Bs[64 * 40];    // [n=64][k=32], stride 40
    const int es  = blockIdx.y;
    const int g0  = blockIdx.x * 128;
    const int tid = threadIdx.x;
    if (tid < 128) sel_s[tid] = sel[(g0 + tid) * 64 + es];
    __syncthreads();

    const int w = tid >> 6, l = tid & 63, quad = l >> 4, lr = l & 15;
    int tokrow[4];
    #pragma unroll
    for (int p = 0; p < 4; ++p) {
        int grow = p * 32 + (tid >> 3);
        tokrow[p] = (g0 + grow) * 16 + sel_s[grow];
    }
    const int c4 = (tid & 7) * 4;
    const int bf = tid >> 2, bd = (tid & 3) * 8;    // B staging: row f, 8-d chunk
    const bf16* f1es = f1p + (size_t)es * (DM * ESZ);

    f32x4 acc[2][4];
    #pragma unroll
    for (int mt = 0; mt < 2; ++mt)
        #pragma unroll
        for (int nt = 0; nt < 4; ++nt)
            acc[mt][nt] = (f32x4){0.f, 0.f, 0.f, 0.f};

    for (int k0 = 0; k0 < DM; k0 += 32) {
        #pragma unroll
        for (int p = 0; p < 4; ++p) {
            int grow = p * 32 + (tid >> 3);
            float4 v = *(const float4*)(x + (size_t)tokrow[p] * DM + k0 + c4);
            bf16x4 ob = {(bf16)v.x, (bf16)v.y, (bf16)v.z, (bf16)v.w};
            *(bf16x4*)(As + grow * 40 + c4) = ob;
        }
        {   // B: contiguous copy (no transpose)
            bf16x8 v = *(const bf16x8*)(f1es + bf * 1024 + k0 + bd);
            *(bf16x8*)(Bs + bf * 40 + bd) = v;
        }
        __syncthreads();
        bf16x8 av[2], bv[4];
        #pragma unroll
        for (int mt = 0; mt < 2; ++mt)
            av[mt] = *(const bf16x8*)(As + (w * 32 + mt * 16 + lr) * 40 + quad * 8);
        #pragma unroll
        for (int nt = 0; nt < 4; ++nt)
            bv[nt] = *(const bf16x8*)(Bs + (nt * 16 + lr) * 40 + quad * 8);
        #pragma unroll
        for (int mt = 0; mt < 2; ++mt)
            #pragma unroll
            for (int nt = 0; nt < 4; ++nt)
                acc[mt][nt] = __builtin_amdgcn_mfma_f32_16x16x32_bf16(
                    av[mt], bv[nt], acc[mt][nt], 0, 0, 0);
        __syncthreads();
    }
    bf16* innes = inner + (size_t)es * (NG * ESZ);
    #pragma unroll
    for (int mt = 0; mt < 2; ++mt)
        #pragma unroll
        for (int nt = 0; nt < 4; ++nt) {
            int f = nt * 16 + lr;
            float b = bias[es * 64 + f];
            #pragma unroll
            for (int r = 0; r < 4; ++r) {
                int grow = w * 32 + mt * 16 + quad * 4 + r;
                float v = acc[mt][nt][r] + b;
                v = v > 0.f ? v : 0.f;
                innes[(size_t)(g0 + grow) * 64 + f] = (bf16)v;
            }
        }
}

// ---------------- K3: FFN2 + un-permute scatter (barrier-free es-loop) ----
// Block = 32 groups x 32 d, 256 threads (4 waves, wave w -> m-half w>>1,
// n-half w&1). A/B fragments load DIRECTLY from global (row-major [row][64]
// bf16 == exact MFMA fragment layout, fully coalesced), 1-deep register
// prefetch, no per-es barriers. LDS = 64KB token-space accumulator with
// XOR-swizzled columns (unique owner per address -> race-free scatter).
__global__ __launch_bounds__(256) void k3_ffn2(const bf16* __restrict__ inner,
                                               const bf16* __restrict__ f2t,
                                               const int* __restrict__ sel,
                                               float* __restrict__ out) {
    __shared__ float accs[512 * 32];   // [gl*16+t][swizzled d-col], 64KB
    const int d0  = blockIdx.x * 32;
    const int g0  = blockIdx.y * 32;
    const int tid = threadIdx.x;
    #pragma unroll
    for (int i = 0; i < 16; ++i)
        ((float4*)accs)[i * 256 + tid] = (float4){0.f, 0.f, 0.f, 0.f};

    const int w = tid >> 6, l = tid & 63, quad = l >> 4, lr = l & 15;
    const int mh = w >> 1, nh = w & 1;
    const bf16* pa = inner + (size_t)(g0 + mh * 16 + lr) * 64 + quad * 8;
    const bf16* pb = f2t   + (size_t)(d0 + nh * 16 + lr) * 64 + quad * 8;
    const int*  ps = sel + (g0 + mh * 16 + quad * 4) * 64;   // rows gl..gl+3

    bf16x8 a0 = *(const bf16x8*)(pa);
    bf16x8 a1 = *(const bf16x8*)(pa + 32);
    bf16x8 b0 = *(const bf16x8*)(pb);
    bf16x8 b1 = *(const bf16x8*)(pb + 32);
    int t0 = ps[0], t1 = ps[64], t2 = ps[128], t3 = ps[192];
    __syncthreads();   // accs zero-init visible to all

    for (int es = 0; es < NES; ++es) {
        int e2 = es + 1 < NES ? es + 1 : NES - 1;   // branchless prefetch idx
        const bf16* qa = pa + (size_t)e2 * 65536;
        const bf16* qb = pb + (size_t)e2 * 65536;
        bf16x8 na0 = *(const bf16x8*)(qa);
        bf16x8 na1 = *(const bf16x8*)(qa + 32);
        bf16x8 nb0 = *(const bf16x8*)(qb);
        bf16x8 nb1 = *(const bf16x8*)(qb + 32);
        int nt0 = ps[e2], nt1 = ps[64 + e2], nt2 = ps[128 + e2], nt3 = ps[192 + e2];

        f32x4 acc = {0.f, 0.f, 0.f, 0.f};
        acc = __builtin_amdgcn_mfma_f32_16x16x32_bf16(a0, b0, acc, 0, 0, 0);
        acc = __builtin_amdgcn_mfma_f32_16x16x32_bf16(a1, b1, acc, 0, 0, 0);
        int tt[4] = {t0, t1, t2, t3};
        #pragma unroll
        for (int r = 0; r < 4; ++r) {
            int gl   = mh * 16 + quad * 4 + r;
            int t    = tt[r];
            int row  = gl * 16 + t;
            int col  = nh * 16 + lr;
            int scol = col ^ ((t & 7) << 2);      // kill 4-way bank conflict
            accs[row * 32 + scol] += acc[r];
        }
        a0 = na0; a1 = na1; b0 = nb0; b1 = nb1;
        t0 = nt0; t1 = nt1; t2 = nt2; t3 = nt3;
    }
    __syncthreads();
    // dense write-out (un-swizzle cols; every output element written once)
    #pragma unroll
    for (int i = 0; i < 16; ++i) {
        int fi = i * 256 + tid;
        int row = fi >> 3, q = fi & 7;
        int scol4 = (q * 4) ^ ((row & 7) << 2);
        float4 v = *(float4*)(accs + row * 32 + scol4);
        *(float4*)(out + (size_t)(g0 * 16 + row) * DM + d0 + q * 4) = v;
    }
}

extern "C" void kernel_launch(void* const* d_in, const int* in_sizes, int n_in,
                              void* d_out, int out_size, void* d_ws, size_t ws_size,
                              hipStream_t stream) {
    const float* x    = (const float*)d_in[0];
    const float* ctrl = (const float*)d_in[1];
    const float* f1   = (const float*)d_in[2];
    const float* f2   = (const float*)d_in[3];
    const float* bias = (const float*)d_in[4];
    float* out = (float*)d_out;

    char* ws = (char*)d_ws;
    bf16* f1p   = (bf16*)(ws);                  // 8,388,608 B
    bf16* f2t   = (bf16*)(ws + 8388608);        // 8,388,608 B
    bf16* inner = (bf16*)(ws + 16777216);       // 8,388,608 B
    int*  sel   = (int*)(ws + 25165824);        //   262,144 B

    hipLaunchKernelGGL(k0_transpose, dim3(16, 64), dim3(256), 0, stream, f1, f2, f1p, f2t);
    hipLaunchKernelGGL(k1_logits,    dim3(1024),   dim3(256), 0, stream, x, ctrl, sel);
    hipLaunchKernelGGL(k2_ffn1,      dim3(8, 64),  dim3(256), 0, stream, x, f1p, bias, sel, inner);
    hipLaunchKernelGGL(k3_ffn2,      dim3(32, 32), dim3(256), 0, stream, inner, f2t, sel, out);
}